// Round 1
// baseline (549.250 us; speedup 1.0000x reference)
//
#include <hip/hip_runtime.h>

#define NW 32
#define BATCH 2048
#define BIGF 1e9f

// One DPP u32-min step (row_shr within 16-lane rows). bound_ctrl=false:
// invalid-source lanes keep old value = min identity.
template <int CTRL>
__device__ __forceinline__ unsigned dpp_umin_step(unsigned x) {
    unsigned t = (unsigned)__builtin_amdgcn_update_dpp((int)x, (int)x, CTRL, 0xF, 0xF, false);
    return t < x ? t : x;
}

// Packed-key min over lanes 0..31 (others must hold ~0u): 4 DPP row_shr steps
// leave min(0..15) at lane 15, min(16..31) at lane 31; merge as scalars.
__device__ __forceinline__ unsigned wave_umin32_key(unsigned red) {
    red = dpp_umin_step<0x111>(red);   // row_shr:1
    red = dpp_umin_step<0x112>(red);   // row_shr:2
    red = dpp_umin_step<0x114>(red);   // row_shr:4
    red = dpp_umin_step<0x118>(red);   // row_shr:8
    unsigned kA = (unsigned)__builtin_amdgcn_readlane((int)red, 15);
    unsigned kB = (unsigned)__builtin_amdgcn_readlane((int)red, 31);
    return kA < kB ? kA : kB;
}

__device__ __forceinline__ float readlane_f(float v, int lane) {
    return __int_as_float(__builtin_amdgcn_readlane(__float_as_int(v), lane));
}

// Register-file "row read": cost[i][col], where each lane holds its column in
// cc[0..31]. 31 v_cndmask tree (~62cy issue, ~20cy latency) replaces the
// dependent ds_read (~120cy stall) that sat on the SAP critical chain.
// All array indices are compile-time constants (runtime-indexed register
// arrays would spill to scratch). Works for wave-uniform i (SGPR masks) and
// per-lane i (vcc masks) identically.
__device__ __forceinline__ float sel32(const float (&cc)[NW], int i) {
    float a[16];
#pragma unroll
    for (int k = 0; k < 16; ++k) a[k] = (i & 1) ? cc[2 * k + 1] : cc[2 * k];
    float b8[8];
#pragma unroll
    for (int k = 0; k < 8; ++k) b8[k] = (i & 2) ? a[2 * k + 1] : a[2 * k];
    float c4[4];
#pragma unroll
    for (int k = 0; k < 4; ++k) c4[k] = (i & 4) ? b8[2 * k + 1] : b8[2 * k];
    float d2[2];
#pragma unroll
    for (int k = 0; k < 2; ++k) d2[k] = (i & 8) ? c4[2 * k + 1] : c4[2 * k];
    return (i & 16) ? d2[1] : d2[0];
}

__global__ __launch_bounds__(64) void floorplan_hungarian_kernel(
    const float* __restrict__ params_true,
    const float* __restrict__ params_pred,
    float* __restrict__ out)
{
    const int b    = blockIdx.x;
    const int lane = threadIdx.x;           // 0..63, one full wave

    // Stride-12 rows: featX[i][0..3] and [4..7] are 16B-aligned -> ds_read_b128
    __shared__ __align__(16) float featT[NW][12];
    __shared__ __align__(16) float featP[NW][12];
    __shared__ int rw[NW];                  // CR: winning column per row

    // ---------------- Phase 1: per-wall features (1 wall per lane) -------------
    {
        const float* src = (lane < NW)
            ? (params_true + ((size_t)b * NW + lane) * 6)
            : (params_pred + ((size_t)b * NW + (lane - NW)) * 6);
        float sx = src[0], sy = src[1], ex = src[2], ey = src[3];
        float w  = src[4], prob = src[5];

        float dx = ex - sx, dy = ey - sy;
        float cx = (sx + ex) * 0.5f, cy = (sy + ey) * 0.5f;
        float len = sqrtf(dx * dx + dy * dy);
        float area = len * w;

        float smaller = fminf(w, len), bigger = fmaxf(w, len);
        float sr = (bigger > 0.0f) ? (smaller / bigger) : 0.0f;

        float px = dy, py = -dx;
        float pd = len;
        if (pd > 0.0f) { px /= pd; py /= pd; }
        px *= w * 0.5f; py *= w * 0.5f;
        float right = fmaxf(fmaxf(sx + px, sx - px), fmaxf(ex + px, ex - px));
        float top   = fmaxf(fmaxf(sy + py, sy - py), fmaxf(ey + py, ey - py));
        float bbw = fabsf((right - cx) * 2.0f);
        float bbh = fabsf((top   - cy) * 2.0f);
        float bba = bbw * bbh;
        float ar  = (bba > 0.001f) ? (area / bba) : 1.0f;

        float* f = (lane < NW) ? featT[lane] : featP[lane - NW];
        f[0] = cx;  f[1] = cy;  f[2] = area; f[3] = sr;
        f[4] = ar;  f[5] = bbw; f[6] = bbh;  f[7] = prob;
    }
    if (lane < NW) rw[lane] = 64;           // CR winner init
    __syncthreads();

    const bool isCol = lane < NW;
    const int  col   = lane & 31;

    // ------- Phase 2: full cost column per lane (registers), + column-min ------
    // Both wave halves redundantly hold column (lane&31): no cross-half traffic
    // is ever needed in the hot loops.
    float p0 = featP[col][0], p1 = featP[col][1], p2 = featP[col][2],
          p3 = featP[col][3], p4 = featP[col][4], p5 = featP[col][5],
          p6 = featP[col][6], p7 = featP[col][7];

    float cc[NW];
    float cmin = BIGF; int cargmin = 0;
#pragma unroll
    for (int i = 0; i < NW; ++i) {
        float dcx = featT[i][0] - p0;
        float dcy = featT[i][1] - p1;
        float center_d = dcx * dcx + dcy * dcy;
        float da = featT[i][2] - p2;   float area_d  = da * da;
        float ds = featT[i][3] - p3;   float lwr_d   = ds * ds;
        float dr = featT[i][4] - p4;   float rot_d   = dr * dr;
        float dxw = featT[i][5] - p5;  float horiz_d = dxw * dxw;
        float dyh = featT[i][6] - p6;  float vert_d  = dyh * dyh;
        float probt = featT[i][7];
        float dp = probt - p7;         float prob_d  = dp * dp;
        float param_d = area_d + center_d + rot_d + horiz_d + vert_d + lwr_d;
        float val = 10.0f * prob_d + param_d * probt;
        cc[i] = val;
        if (val < cmin) { cmin = val; cargmin = i; }   // ascending i: first-min
    }

    // --------- CR part 2: deterministic unique-argmin greedy assignment --------
    if (lane < NW) atomicMin(&rw[cargmin], lane);
    __syncthreads();

    float v_col   = isCol ? cmin : 0.0f;    // v = column min (feasible duals)
    float u_row   = 0.0f;
    int   win     = isCol ? rw[lane] : 64;
    int   col4row = (isCol && win < 64) ? win : -1;
    int   row4col = (isCol && rw[cargmin] == lane) ? cargmin : -1;

    unsigned rem      = (unsigned)(__ballot(isCol && col4row < 0) & 0xffffffffull);
    unsigned freeCols = (unsigned)(__ballot(isCol && row4col < 0) & 0xffffffffull);

    // ------- Greedy free-row pass (ART-lite): u_i = min slack; assign if -------
    // the argmin column is free (edge tight, duals stay feasible).
    {
        unsigned g = rem;
        while (g != 0) {
            int i = __ffs(g) - 1;
            g &= (g - 1);
            float cij = sel32(cc, i);                     // register-file row read
            float slack = cij - v_col;                    // >= 0 (v = colmin)
            unsigned key = isCol
                ? ((__float_as_uint(slack) & 0xFFFFFFE0u) | (unsigned)col)
                : 0xFFFFFFFFu;
            unsigned kmin = wave_umin32_key(key);
            int   j1 = (int)(kmin & 31u);
            float m1 = __uint_as_float(kmin & 0xFFFFFFE0u);
            if (lane == i) u_row = m1;                    // tighten dual (feasible)
            if ((freeCols >> j1) & 1u) {                  // assign only if free
                if (lane == j1) row4col = i;
                if (lane == i)  col4row = j1;
                freeCols &= ~(1u << j1);
                rem      &= ~(1u << i);
            }
        }
    }

    // ---------------- SAP: shortest augmenting path for leftover rows ----------
    {
        while (rem != 0) {
            int i0 = __ffs(rem) - 1;
            rem &= (rem - 1);

            bool     SCb     = !isCol;
            unsigned spcKey  = 0xFFFFFFFFu;    // (quantized slack | j), frozen at SC
            int      pathReg = 0;
            unsigned srMask  = 1u << i0;
            float    minValF = 0.0f;
            int      i = i0;
            int      sink;

            float cij = sel32(cc, i);          // register row read (no LDS stall)
            float u_i = readlane_f(u_row, i);
            while (true) {
                float t   = (minValF - v_col) - u_i;
                float slack = fmaxf(t + cij, 0.0f);            // >=0: bits monotone
                unsigned key = (__float_as_uint(slack) & 0xFFFFFFE0u) | (unsigned)col;
                unsigned old = spcKey;
                unsigned mn  = key < spcKey ? key : spcKey;
                spcKey = SCb ? spcKey : mn;                    // freeze when SC
                pathReg = (spcKey != old) ? i : pathReg;       // source row of best
                unsigned red = SCb ? 0xFFFFFFFFu : spcKey;

                unsigned kmin = wave_umin32_key(red);
                int j = (int)(kmin & 31u);                     // index in low bits
                minValF = __uint_as_float(kmin & 0xFFFFFFE0u); // value, quantized
                SCb = SCb || (lane == j);
                int r = __builtin_amdgcn_readlane(row4col, j); // || with bit test
                if ((freeCols >> j) & 1u) { sink = j; break; }
                i = r;
                srMask |= (1u << i);
                cij = sel32(cc, i);                            // prefetch next row
                u_i = readlane_f(u_row, i);                    // || with tree
            }

            // dual updates (spc recovered from frozen keys, quantized)
            {
                float spcF = __uint_as_float(spcKey & 0xFFFFFFE0u);
                int gidx = (col4row < 0) ? 0 : col4row;
                float spc_at_c4r = __shfl(spcF, gidx);
                bool in_SR = isCol && ((srMask >> col) & 1u);
                if (lane == i0)              u_row += minValF;
                else if (in_SR)              u_row += minValF - spc_at_c4r;
                if (isCol && SCb)            v_col -= (minValF - spcF);
            }

            // augment along path
            {
                int j = sink;
                freeCols &= ~(1u << sink);
                while (true) {
                    int ii = __builtin_amdgcn_readlane(pathReg, j);
                    if (lane == j) row4col = ii;
                    int j_next = __builtin_amdgcn_readlane(col4row, ii);
                    if (lane == ii) col4row = j;
                    if (ii == i0) break;
                    j = j_next;
                }
            }
        }
    }

    // ------------- Loss = sum of assigned edge costs (column-wise) -------------
    // Column j contributes cost[row4col[j]][j]: per-lane index into the same
    // register column -> sel32 with per-lane (vcc-mask) selects. Equals the
    // row-wise sum since the matching is a bijection.
    float myedge = (isCol && row4col >= 0) ? sel32(cc, row4col) : 0.0f;
    #pragma unroll
    for (int off = 32; off >= 1; off >>= 1)
        myedge += __shfl_xor(myedge, off);
    if (lane == 0) out[b] = myedge;
}

extern "C" void kernel_launch(void* const* d_in, const int* in_sizes, int n_in,
                              void* d_out, int out_size, void* d_ws, size_t ws_size,
                              hipStream_t stream) {
    const float* params_true = (const float*)d_in[0];
    const float* params_pred = (const float*)d_in[1];
    float* out = (float*)d_out;
    floorplan_hungarian_kernel<<<BATCH, 64, 0, stream>>>(params_true, params_pred, out);
}

// Round 2
// 182.434 us; speedup vs baseline: 3.0107x; 3.0107x over previous
//
#include <hip/hip_runtime.h>

#define NW 32
#define BATCH 2048
#define BIGF 1e9f

// One DPP u32-min step (row_shr within 16-lane rows). bound_ctrl=false:
// invalid-source lanes keep old value = min identity.
template <int CTRL>
__device__ __forceinline__ unsigned dpp_umin_step(unsigned x) {
    unsigned t = (unsigned)__builtin_amdgcn_update_dpp((int)x, (int)x, CTRL, 0xF, 0xF, false);
    return t < x ? t : x;
}

// Packed-key min over lanes 0..31 (others must hold ~0u): 4 DPP row_shr steps
// leave min(0..15) at lane 15, min(16..31) at lane 31; merge as scalars.
__device__ __forceinline__ unsigned wave_umin32_key(unsigned red) {
    red = dpp_umin_step<0x111>(red);   // row_shr:1
    red = dpp_umin_step<0x112>(red);   // row_shr:2
    red = dpp_umin_step<0x114>(red);   // row_shr:4
    red = dpp_umin_step<0x118>(red);   // row_shr:8
    unsigned kA = (unsigned)__builtin_amdgcn_readlane((int)red, 15);
    unsigned kB = (unsigned)__builtin_amdgcn_readlane((int)red, 31);
    return kA < kB ? kA : kB;
}

__device__ __forceinline__ float readlane_f(float v, int lane) {
    return __int_as_float(__builtin_amdgcn_readlane(__float_as_int(v), lane));
}

// Register-file "row read": cost[i][col] where lane holds its column in 32
// NAMED scalars c0..c31 (named scalars cannot be demoted to a scratch alloca
// — the round-1 float cc[32] version spilled: VGPR_Count=20, 1.15 GB/dispatch
// scratch writes). 31 v_cndmask tree, depth 5, all indices compile-time.
// Works for wave-uniform idx (scalar cond) and per-lane idx (vcc) identically.
#define SEL32(dst, idx) do {                                                   \
    const int  _s  = (idx);                                                    \
    const bool _b0 = (_s & 1),  _b1 = (_s & 2),  _b2 = (_s & 4);               \
    const bool _b3 = (_s & 8),  _b4 = (_s & 16);                               \
    float _a0 = _b0 ? c1  : c0,  _a1 = _b0 ? c3  : c2;                         \
    float _a2 = _b0 ? c5  : c4,  _a3 = _b0 ? c7  : c6;                         \
    float _a4 = _b0 ? c9  : c8,  _a5 = _b0 ? c11 : c10;                        \
    float _a6 = _b0 ? c13 : c12, _a7 = _b0 ? c15 : c14;                        \
    float _a8 = _b0 ? c17 : c16, _a9 = _b0 ? c19 : c18;                        \
    float _aA = _b0 ? c21 : c20, _aB = _b0 ? c23 : c22;                        \
    float _aC = _b0 ? c25 : c24, _aD = _b0 ? c27 : c26;                        \
    float _aE = _b0 ? c29 : c28, _aF = _b0 ? c31 : c30;                        \
    float _e0 = _b1 ? _a1 : _a0, _e1 = _b1 ? _a3 : _a2;                        \
    float _e2 = _b1 ? _a5 : _a4, _e3 = _b1 ? _a7 : _a6;                        \
    float _e4 = _b1 ? _a9 : _a8, _e5 = _b1 ? _aB : _aA;                        \
    float _e6 = _b1 ? _aD : _aC, _e7 = _b1 ? _aF : _aE;                        \
    float _f0 = _b2 ? _e1 : _e0, _f1 = _b2 ? _e3 : _e2;                        \
    float _f2 = _b2 ? _e5 : _e4, _f3 = _b2 ? _e7 : _e6;                        \
    float _g0 = _b3 ? _f1 : _f0, _g1 = _b3 ? _f3 : _f2;                        \
    (dst) = _b4 ? _g1 : _g0;                                                   \
} while (0)

// Cost of edge (row i, this lane's column): identical arithmetic/order to the
// verified round-0 kernel. Ascending-i strict < keeps first-min (tie rule).
#define COST_ROW(i, dst) do {                                                  \
    float dcx = featT[i][0] - p0;                                              \
    float dcy = featT[i][1] - p1;                                              \
    float center_d = dcx * dcx + dcy * dcy;                                    \
    float da  = featT[i][2] - p2;   float area_d  = da * da;                   \
    float ds  = featT[i][3] - p3;   float lwr_d   = ds * ds;                   \
    float dr  = featT[i][4] - p4;   float rot_d   = dr * dr;                   \
    float dxw = featT[i][5] - p5;   float horiz_d = dxw * dxw;                 \
    float dyh = featT[i][6] - p6;   float vert_d  = dyh * dyh;                 \
    float probt = featT[i][7];                                                 \
    float dp  = probt - p7;         float prob_d  = dp * dp;                   \
    float param_d = area_d + center_d + rot_d + horiz_d + vert_d + lwr_d;      \
    float val = 10.0f * prob_d + param_d * probt;                              \
    (dst) = val;                                                               \
    if (val < cmin) { cmin = val; cargmin = (i); }                             \
} while (0)

__global__ __launch_bounds__(64) void floorplan_hungarian_kernel(
    const float* __restrict__ params_true,
    const float* __restrict__ params_pred,
    float* __restrict__ out)
{
    const int b    = blockIdx.x;
    const int lane = threadIdx.x;           // 0..63, one full wave

    // Stride-12 rows: featX[i][0..3] and [4..7] are 16B-aligned -> ds_read_b128
    __shared__ __align__(16) float featT[NW][12];
    __shared__ __align__(16) float featP[NW][12];
    __shared__ int rw[NW];                  // CR: winning column per row

    // ---------------- Phase 1: per-wall features (1 wall per lane) -------------
    {
        const float* src = (lane < NW)
            ? (params_true + ((size_t)b * NW + lane) * 6)
            : (params_pred + ((size_t)b * NW + (lane - NW)) * 6);
        float sx = src[0], sy = src[1], ex = src[2], ey = src[3];
        float w  = src[4], prob = src[5];

        float dx = ex - sx, dy = ey - sy;
        float cx = (sx + ex) * 0.5f, cy = (sy + ey) * 0.5f;
        float len = sqrtf(dx * dx + dy * dy);
        float area = len * w;

        float smaller = fminf(w, len), bigger = fmaxf(w, len);
        float sr = (bigger > 0.0f) ? (smaller / bigger) : 0.0f;

        float px = dy, py = -dx;
        float pd = len;
        if (pd > 0.0f) { px /= pd; py /= pd; }
        px *= w * 0.5f; py *= w * 0.5f;
        float right = fmaxf(fmaxf(sx + px, sx - px), fmaxf(ex + px, ex - px));
        float top   = fmaxf(fmaxf(sy + py, sy - py), fmaxf(ey + py, ey - py));
        float bbw = fabsf((right - cx) * 2.0f);
        float bbh = fabsf((top   - cy) * 2.0f);
        float bba = bbw * bbh;
        float ar  = (bba > 0.001f) ? (area / bba) : 1.0f;

        float* f = (lane < NW) ? featT[lane] : featP[lane - NW];
        f[0] = cx;  f[1] = cy;  f[2] = area; f[3] = sr;
        f[4] = ar;  f[5] = bbw; f[6] = bbh;  f[7] = prob;
    }
    if (lane < NW) rw[lane] = 64;           // CR winner init
    __syncthreads();

    const bool isCol = lane < NW;
    const int  col   = lane & 31;

    // ------- Phase 2: full cost column per lane (registers), + column-min ------
    // Both wave halves redundantly hold column (lane&31): no cross-half traffic
    // is ever needed in the hot loops.
    float p0 = featP[col][0], p1 = featP[col][1], p2 = featP[col][2],
          p3 = featP[col][3], p4 = featP[col][4], p5 = featP[col][5],
          p6 = featP[col][6], p7 = featP[col][7];

    float cmin = BIGF; int cargmin = 0;
    float c0,  c1,  c2,  c3,  c4,  c5,  c6,  c7,
          c8,  c9,  c10, c11, c12, c13, c14, c15,
          c16, c17, c18, c19, c20, c21, c22, c23,
          c24, c25, c26, c27, c28, c29, c30, c31;
    COST_ROW(0,  c0);  COST_ROW(1,  c1);  COST_ROW(2,  c2);  COST_ROW(3,  c3);
    COST_ROW(4,  c4);  COST_ROW(5,  c5);  COST_ROW(6,  c6);  COST_ROW(7,  c7);
    COST_ROW(8,  c8);  COST_ROW(9,  c9);  COST_ROW(10, c10); COST_ROW(11, c11);
    COST_ROW(12, c12); COST_ROW(13, c13); COST_ROW(14, c14); COST_ROW(15, c15);
    COST_ROW(16, c16); COST_ROW(17, c17); COST_ROW(18, c18); COST_ROW(19, c19);
    COST_ROW(20, c20); COST_ROW(21, c21); COST_ROW(22, c22); COST_ROW(23, c23);
    COST_ROW(24, c24); COST_ROW(25, c25); COST_ROW(26, c26); COST_ROW(27, c27);
    COST_ROW(28, c28); COST_ROW(29, c29); COST_ROW(30, c30); COST_ROW(31, c31);

    // --------- CR part 2: deterministic unique-argmin greedy assignment --------
    if (lane < NW) atomicMin(&rw[cargmin], lane);
    __syncthreads();

    float v_col   = isCol ? cmin : 0.0f;    // v = column min (feasible duals)
    float u_row   = 0.0f;
    int   win     = isCol ? rw[lane] : 64;
    int   col4row = (isCol && win < 64) ? win : -1;
    int   row4col = (isCol && rw[cargmin] == lane) ? cargmin : -1;

    unsigned rem      = (unsigned)(__ballot(isCol && col4row < 0) & 0xffffffffull);
    unsigned freeCols = (unsigned)(__ballot(isCol && row4col < 0) & 0xffffffffull);

    // ------- Greedy free-row pass (ART-lite): u_i = min slack; assign if -------
    // the argmin column is free (edge tight, duals stay feasible).
    {
        unsigned g = rem;
        while (g != 0) {
            int i = __ffs(g) - 1;
            g &= (g - 1);
            float cij; SEL32(cij, i);                     // register-file row read
            float slack = cij - v_col;                    // >= 0 (v = colmin)
            unsigned key = isCol
                ? ((__float_as_uint(slack) & 0xFFFFFFE0u) | (unsigned)col)
                : 0xFFFFFFFFu;
            unsigned kmin = wave_umin32_key(key);
            int   j1 = (int)(kmin & 31u);
            float m1 = __uint_as_float(kmin & 0xFFFFFFE0u);
            if (lane == i) u_row = m1;                    // tighten dual (feasible)
            if ((freeCols >> j1) & 1u) {                  // assign only if free
                if (lane == j1) row4col = i;
                if (lane == i)  col4row = j1;
                freeCols &= ~(1u << j1);
                rem      &= ~(1u << i);
            }
        }
    }

    // ---------------- SAP: shortest augmenting path for leftover rows ----------
    {
        while (rem != 0) {
            int i0 = __ffs(rem) - 1;
            rem &= (rem - 1);

            bool     SCb     = !isCol;
            unsigned spcKey  = 0xFFFFFFFFu;    // (quantized slack | j), frozen at SC
            int      pathReg = 0;
            unsigned srMask  = 1u << i0;
            float    minValF = 0.0f;
            int      i = i0;
            int      sink;

            float cij; SEL32(cij, i);          // register row read (no LDS stall)
            float u_i = readlane_f(u_row, i);
            while (true) {
                float t   = (minValF - v_col) - u_i;
                float slack = fmaxf(t + cij, 0.0f);            // >=0: bits monotone
                unsigned key = (__float_as_uint(slack) & 0xFFFFFFE0u) | (unsigned)col;
                unsigned old = spcKey;
                unsigned mn  = key < spcKey ? key : spcKey;
                spcKey = SCb ? spcKey : mn;                    // freeze when SC
                pathReg = (spcKey != old) ? i : pathReg;       // source row of best
                unsigned red = SCb ? 0xFFFFFFFFu : spcKey;

                unsigned kmin = wave_umin32_key(red);
                int j = (int)(kmin & 31u);                     // index in low bits
                minValF = __uint_as_float(kmin & 0xFFFFFFE0u); // value, quantized
                SCb = SCb || (lane == j);
                int r = __builtin_amdgcn_readlane(row4col, j); // || with bit test
                if ((freeCols >> j) & 1u) { sink = j; break; }
                i = r;
                srMask |= (1u << i);
                SEL32(cij, i);                                 // prefetch next row
                u_i = readlane_f(u_row, i);                    // || with tree
            }

            // dual updates (spc recovered from frozen keys, quantized)
            {
                float spcF = __uint_as_float(spcKey & 0xFFFFFFE0u);
                int gidx = (col4row < 0) ? 0 : col4row;
                float spc_at_c4r = __shfl(spcF, gidx);
                bool in_SR = isCol && ((srMask >> col) & 1u);
                if (lane == i0)              u_row += minValF;
                else if (in_SR)              u_row += minValF - spc_at_c4r;
                if (isCol && SCb)            v_col -= (minValF - spcF);
            }

            // augment along path
            {
                int j = sink;
                freeCols &= ~(1u << sink);
                while (true) {
                    int ii = __builtin_amdgcn_readlane(pathReg, j);
                    if (lane == j) row4col = ii;
                    int j_next = __builtin_amdgcn_readlane(col4row, ii);
                    if (lane == ii) col4row = j;
                    if (ii == i0) break;
                    j = j_next;
                }
            }
        }
    }

    // ------------- Loss = sum of assigned edge costs (column-wise) -------------
    // Column j contributes cost[row4col[j]][j]: per-lane index into the same
    // register column -> SEL32 with per-lane (vcc-mask) selects. Equals the
    // row-wise sum since the matching is a bijection.
    {
        int rsel = (row4col >= 0) ? row4col : 0;
        float val; SEL32(val, rsel);
        float myedge = (isCol && row4col >= 0) ? val : 0.0f;
        #pragma unroll
        for (int off = 32; off >= 1; off >>= 1)
            myedge += __shfl_xor(myedge, off);
        if (lane == 0) out[b] = myedge;
    }
}

extern "C" void kernel_launch(void* const* d_in, const int* in_sizes, int n_in,
                              void* d_out, int out_size, void* d_ws, size_t ws_size,
                              hipStream_t stream) {
    const float* params_true = (const float*)d_in[0];
    const float* params_pred = (const float*)d_in[1];
    float* out = (float*)d_out;
    floorplan_hungarian_kernel<<<BATCH, 64, 0, stream>>>(params_true, params_pred, out);
}

// Round 3
// 153.609 us; speedup vs baseline: 3.5756x; 1.1876x over previous
//
#include <hip/hip_runtime.h>

#define NW 32
#define BATCH 2048
#define BIGF 1e9f

// One DPP u32-min step (row_shr within 16-lane rows). bound_ctrl=false:
// invalid-source lanes keep old value = min identity.
template <int CTRL>
__device__ __forceinline__ unsigned dpp_umin_step(unsigned x) {
    unsigned t = (unsigned)__builtin_amdgcn_update_dpp((int)x, (int)x, CTRL, 0xF, 0xF, false);
    return t < x ? t : x;
}

// Packed-key min over lanes 0..31 (others must hold ~0u): 4 DPP row_shr steps
// leave min(0..15) at lane 15, min(16..31) at lane 31; merge as scalars.
__device__ __forceinline__ unsigned wave_umin32_key(unsigned red) {
    red = dpp_umin_step<0x111>(red);   // row_shr:1
    red = dpp_umin_step<0x112>(red);   // row_shr:2
    red = dpp_umin_step<0x114>(red);   // row_shr:4
    red = dpp_umin_step<0x118>(red);   // row_shr:8
    unsigned kA = (unsigned)__builtin_amdgcn_readlane((int)red, 15);
    unsigned kB = (unsigned)__builtin_amdgcn_readlane((int)red, 31);
    return kA < kB ? kA : kB;
}

__device__ __forceinline__ float readlane_f(float v, int lane) {
    return __int_as_float(__builtin_amdgcn_readlane(__float_as_int(v), lane));
}

__global__ __launch_bounds__(64) void floorplan_hungarian_kernel(
    const float* __restrict__ params_true,
    const float* __restrict__ params_pred,
    float* __restrict__ out)
{
    const int b    = blockIdx.x;
    const int lane = threadIdx.x;           // 0..63, one full wave

    __shared__ float cost[NW][NW + 1];      // padded rows: conflict-free
    __shared__ float featT[NW][9];
    __shared__ float featP[NW][9];
    __shared__ int   rw[NW];                // CR: winning column per row

    // ---------------- Phase 1: per-wall features (1 wall per lane) -------------
    {
        const float* src = (lane < NW)
            ? (params_true + ((size_t)b * NW + lane) * 6)
            : (params_pred + ((size_t)b * NW + (lane - NW)) * 6);
        float sx = src[0], sy = src[1], ex = src[2], ey = src[3];
        float w  = src[4], prob = src[5];

        float dx = ex - sx, dy = ey - sy;
        float cx = (sx + ex) * 0.5f, cy = (sy + ey) * 0.5f;
        float len = sqrtf(dx * dx + dy * dy);
        float area = len * w;

        float smaller = fminf(w, len), bigger = fmaxf(w, len);
        float sr = (bigger > 0.0f) ? (smaller / bigger) : 0.0f;

        float px = dy, py = -dx;
        float pd = len;
        if (pd > 0.0f) { px /= pd; py /= pd; }
        px *= w * 0.5f; py *= w * 0.5f;
        float right = fmaxf(fmaxf(sx + px, sx - px), fmaxf(ex + px, ex - px));
        float top   = fmaxf(fmaxf(sy + py, sy - py), fmaxf(ey + py, ey - py));
        float bbw = fabsf((right - cx) * 2.0f);
        float bbh = fabsf((top   - cy) * 2.0f);
        float bba = bbw * bbh;
        float ar  = (bba > 0.001f) ? (area / bba) : 1.0f;

        float* f = (lane < NW) ? featT[lane] : featP[lane - NW];
        f[0] = cx;  f[1] = cy;  f[2] = area; f[3] = sr;
        f[4] = ar;  f[5] = bbw; f[6] = bbh;  f[7] = prob;
    }
    if (lane < NW) rw[lane] = 64;           // CR winner init
    __syncthreads();

    // ------- Phase 2: 32x32 cost matrix + fused column-min (CR part 1) --------
    float cmin = BIGF; int cargmin = 0;
    for (int e = lane; e < NW * NW; e += 64) {
        int i = e >> 5, j = e & 31;
        float dcx = featT[i][0] - featP[j][0];
        float dcy = featT[i][1] - featP[j][1];
        float center_d = dcx * dcx + dcy * dcy;
        float da = featT[i][2] - featP[j][2];   float area_d  = da * da;
        float ds = featT[i][3] - featP[j][3];   float lwr_d   = ds * ds;
        float dr = featT[i][4] - featP[j][4];   float rot_d   = dr * dr;
        float dxw = featT[i][5] - featP[j][5];  float horiz_d = dxw * dxw;
        float dyh = featT[i][6] - featP[j][6];  float vert_d  = dyh * dyh;
        float probt = featT[i][7], probp = featP[j][7];
        float dp = probt - probp;               float prob_d  = dp * dp;
        float param_d = area_d + center_d + rot_d + horiz_d + vert_d + lwr_d;
        float val = 10.0f * prob_d + param_d * probt;
        cost[i][j] = val;
        if (val < cmin) { cmin = val; cargmin = i; }   // rows ascending: first-min
    }
    {
        float om = __shfl_xor(cmin, 32);
        int   oi = __shfl_xor(cargmin, 32);
        if (om < cmin || (om == cmin && oi < cargmin)) { cmin = om; cargmin = oi; }
    }
    __syncthreads();

    // --------- CR part 2: deterministic unique-argmin greedy assignment --------
    if (lane < NW) atomicMin(&rw[cargmin], lane);
    __syncthreads();

    const bool isCol = lane < NW;
    const int  col   = lane & 31;
    float v_col   = isCol ? cmin : 0.0f;    // v = column min (feasible duals)
    float u_row   = 0.0f;
    int   win     = isCol ? rw[lane] : 64;
    int   col4row = (isCol && win < 64) ? win : -1;
    int   row4col = (isCol && rw[cargmin] == lane) ? cargmin : -1;
    __syncthreads();

    unsigned rem      = (unsigned)(__ballot(isCol && col4row < 0) & 0xffffffffull);
    unsigned freeCols = (unsigned)(__ballot(isCol && row4col < 0) & 0xffffffffull);

    // ------- ART (JV augmenting row reduction): min + second-min; steal --------
    // Per free row i: m1,j1 = min slack, m2 = second min. u_i += m2,
    // v[j1] -= (m2-m1) keeps duals feasible with (i,j1) eps-tight under the
    // same 27-bit key truncation the rest of the solver uses (trunc rounds
    // down, monotone). Assign i->j1 even if occupied (steal, requeue victim;
    // each steal drops v[j1] by >= 1 quantum -> progress). Quantized ties on
    // an occupied column could ping-pong -> defer those rows to SAP. Safety
    // cap dumps any leftovers to SAP, so correctness never depends on ART.
    {
        unsigned q = rem;                   // free-row work queue
        rem = 0u;                           // rows deferred to SAP
        int guard = 128;
        while (q != 0 && guard-- > 0) {
            int i = __ffs(q) - 1;
            q &= (q - 1);
            float u_i = readlane_f(u_row, i);
            float cij = cost[i][col];
            float slack = fmaxf(cij - u_i - v_col, 0.0f);  // >=0: bits monotone
            unsigned key = isCol
                ? ((__float_as_uint(slack) & 0xFFFFFFE0u) | (unsigned)col)
                : 0xFFFFFFFFu;
            unsigned k1  = wave_umin32_key(key);
            int      j1  = (int)(k1 & 31u);
            unsigned m1q = k1 & 0xFFFFFFE0u;
            unsigned key2 = (col == j1) ? 0xFFFFFFFFu : key;  // mask winner col
            unsigned k2  = wave_umin32_key(key2);
            unsigned m2q = k2 & 0xFFFFFFE0u;
            float m1f = __uint_as_float(m1q);
            float m2f = __uint_as_float(m2q);
            if (lane == i) u_row += m2f;                   // tighten row dual
            int  kprev  = __builtin_amdgcn_readlane(row4col, j1);
            bool j1free = (freeCols >> j1) & 1u;
            if (j1free || m1q < m2q) {
                if (lane == j1) { v_col -= (m2f - m1f); row4col = i; }
                if (lane == i)  col4row = j1;
                if (j1free) {
                    freeCols &= ~(1u << j1);
                } else {                                   // steal from kprev
                    if (lane == kprev) col4row = -1;
                    q |= (1u << kprev);                    // requeue victim
                }
            } else {
                rem |= (1u << i);          // quantized tie on occupied col
            }
        }
        rem |= q;                          // guard spill-over (rare) -> SAP
    }

    // ---------------- SAP: shortest augmenting path for leftover rows ----------
    {
        while (rem != 0) {
            int i0 = __ffs(rem) - 1;
            rem &= (rem - 1);

            bool     SCb     = !isCol;
            unsigned spcKey  = 0xFFFFFFFFu;    // (quantized slack | j), frozen at SC
            int      pathReg = 0;
            unsigned srMask  = 1u << i0;
            float    minValF = 0.0f;
            int      i = i0;
            int      sink;

            float cij = cost[i][col];          // prefetched cost row
            while (true) {
                float u_i = readlane_f(u_row, i);              // || with ds_read
                float t   = (minValF - v_col) - u_i;           // || with ds_read
                float slack = fmaxf(t + cij, 0.0f);            // >=0: bits monotone
                unsigned key = (__float_as_uint(slack) & 0xFFFFFFE0u) | (unsigned)col;
                unsigned old = spcKey;
                unsigned mn  = key < spcKey ? key : spcKey;
                spcKey = SCb ? spcKey : mn;                    // freeze when SC
                pathReg = (spcKey != old) ? i : pathReg;       // source row of best
                unsigned red = SCb ? 0xFFFFFFFFu : spcKey;

                unsigned kmin = wave_umin32_key(red);
                int j = (int)(kmin & 31u);                     // index in low bits
                minValF = __uint_as_float(kmin & 0xFFFFFFE0u); // value, quantized
                SCb = SCb || (lane == j);
                int r = __builtin_amdgcn_readlane(row4col, j); // || with bit test
                if ((freeCols >> j) & 1u) { sink = j; break; }
                i = r;
                srMask |= (1u << i);
                cij = cost[i][col];                            // prefetch next row
            }

            // dual updates (spc recovered from frozen keys, quantized)
            {
                float spcF = __uint_as_float(spcKey & 0xFFFFFFE0u);
                int gidx = (col4row < 0) ? 0 : col4row;
                float spc_at_c4r = __shfl(spcF, gidx);
                bool in_SR = isCol && ((srMask >> col) & 1u);
                if (lane == i0)              u_row += minValF;
                else if (in_SR)              u_row += minValF - spc_at_c4r;
                if (isCol && SCb)            v_col -= (minValF - spcF);
            }

            // augment along path
            {
                int j = sink;
                freeCols &= ~(1u << sink);
                while (true) {
                    int ii = __builtin_amdgcn_readlane(pathReg, j);
                    if (lane == j) row4col = ii;
                    int j_next = __builtin_amdgcn_readlane(col4row, ii);
                    if (lane == ii) col4row = j;
                    if (ii == i0) break;
                    j = j_next;
                }
            }
        }
    }

    // ---------------- Loss = sum of assigned edge costs ------------------------
    float myedge = (isCol && col4row >= 0) ? cost[lane][col4row] : 0.0f;
    #pragma unroll
    for (int off = 32; off >= 1; off >>= 1)
        myedge += __shfl_xor(myedge, off);
    if (lane == 0) out[b] = myedge;
}

extern "C" void kernel_launch(void* const* d_in, const int* in_sizes, int n_in,
                              void* d_out, int out_size, void* d_ws, size_t ws_size,
                              hipStream_t stream) {
    const float* params_true = (const float*)d_in[0];
    const float* params_pred = (const float*)d_in[1];
    float* out = (float*)d_out;
    floorplan_hungarian_kernel<<<BATCH, 64, 0, stream>>>(params_true, params_pred, out);
}

// Round 6
// 114.384 us; speedup vs baseline: 4.8018x; 1.3429x over previous
//
#include <hip/hip_runtime.h>

#define NW 32
#define BATCH 2048
#define BIGF 1e9f

// One DPP u32-min step (row_shr within 16-lane rows). bound_ctrl=false:
// invalid-source lanes keep old value = min identity.
template <int CTRL>
__device__ __forceinline__ unsigned dpp_umin_step(unsigned x) {
    unsigned t = (unsigned)__builtin_amdgcn_update_dpp((int)x, (int)x, CTRL, 0xF, 0xF, false);
    return t < x ? t : x;
}

// Packed-key min over lanes 0..31 (others must hold ~0u): 4 DPP row_shr steps
// leave min(0..15) at lane 15, min(16..31) at lane 31; merge as scalars.
__device__ __forceinline__ unsigned wave_umin32_key(unsigned red) {
    red = dpp_umin_step<0x111>(red);   // row_shr:1
    red = dpp_umin_step<0x112>(red);   // row_shr:2
    red = dpp_umin_step<0x114>(red);   // row_shr:4
    red = dpp_umin_step<0x118>(red);   // row_shr:8
    unsigned kA = (unsigned)__builtin_amdgcn_readlane((int)red, 15);
    unsigned kB = (unsigned)__builtin_amdgcn_readlane((int)red, 31);
    return kA < kB ? kA : kB;
}

__device__ __forceinline__ float readlane_f(float v, int lane) {
    return __int_as_float(__builtin_amdgcn_readlane(__float_as_int(v), lane));
}

__global__ __launch_bounds__(64) void floorplan_hungarian_kernel(
    const float* __restrict__ params_true,
    const float* __restrict__ params_pred,
    float* __restrict__ out)
{
    const int b    = blockIdx.x;
    const int lane = threadIdx.x;           // 0..63, one full wave

    __shared__ float cost[NW][NW + 1];      // padded rows: conflict-free
    __shared__ float featT[NW][9];
    __shared__ float featP[NW][9];
    __shared__ int   rw[NW];                // CR: winning column per row
    __shared__ float vsh[NW];               // v duals mirrored for row-scan

    // ---------------- Phase 1: per-wall features (1 wall per lane) -------------
    {
        const float* src = (lane < NW)
            ? (params_true + ((size_t)b * NW + lane) * 6)
            : (params_pred + ((size_t)b * NW + (lane - NW)) * 6);
        float sx = src[0], sy = src[1], ex = src[2], ey = src[3];
        float w  = src[4], prob = src[5];

        float dx = ex - sx, dy = ey - sy;
        float cx = (sx + ex) * 0.5f, cy = (sy + ey) * 0.5f;
        float len = sqrtf(dx * dx + dy * dy);
        float area = len * w;

        float smaller = fminf(w, len), bigger = fmaxf(w, len);
        float sr = (bigger > 0.0f) ? (smaller / bigger) : 0.0f;

        float px = dy, py = -dx;
        float pd = len;
        if (pd > 0.0f) { px /= pd; py /= pd; }
        px *= w * 0.5f; py *= w * 0.5f;
        float right = fmaxf(fmaxf(sx + px, sx - px), fmaxf(ex + px, ex - px));
        float top   = fmaxf(fmaxf(sy + py, sy - py), fmaxf(ey + py, ey - py));
        float bbw = fabsf((right - cx) * 2.0f);
        float bbh = fabsf((top   - cy) * 2.0f);
        float bba = bbw * bbh;
        float ar  = (bba > 0.001f) ? (area / bba) : 1.0f;

        float* f = (lane < NW) ? featT[lane] : featP[lane - NW];
        f[0] = cx;  f[1] = cy;  f[2] = area; f[3] = sr;
        f[4] = ar;  f[5] = bbw; f[6] = bbh;  f[7] = prob;
    }
    if (lane < NW) rw[lane] = 64;           // CR winner init
    __syncthreads();

    // ------- Phase 2: 32x32 cost matrix + fused column-min (CR part 1) --------
    float cmin = BIGF; int cargmin = 0;
    for (int e = lane; e < NW * NW; e += 64) {
        int i = e >> 5, j = e & 31;
        float dcx = featT[i][0] - featP[j][0];
        float dcy = featT[i][1] - featP[j][1];
        float center_d = dcx * dcx + dcy * dcy;
        float da = featT[i][2] - featP[j][2];   float area_d  = da * da;
        float ds = featT[i][3] - featP[j][3];   float lwr_d   = ds * ds;
        float dr = featT[i][4] - featP[j][4];   float rot_d   = dr * dr;
        float dxw = featT[i][5] - featP[j][5];  float horiz_d = dxw * dxw;
        float dyh = featT[i][6] - featP[j][6];  float vert_d  = dyh * dyh;
        float probt = featT[i][7], probp = featP[j][7];
        float dp = probt - probp;               float prob_d  = dp * dp;
        float param_d = area_d + center_d + rot_d + horiz_d + vert_d + lwr_d;
        float val = 10.0f * prob_d + param_d * probt;
        cost[i][j] = val;
        if (val < cmin) { cmin = val; cargmin = i; }   // rows ascending: first-min
    }
    {
        float om = __shfl_xor(cmin, 32);
        int   oi = __shfl_xor(cargmin, 32);
        if (om < cmin || (om == cmin && oi < cargmin)) { cmin = om; cargmin = oi; }
    }
    __syncthreads();

    // --------- CR part 2: deterministic unique-argmin greedy assignment --------
    if (lane < NW) atomicMin(&rw[cargmin], lane);
    __syncthreads();

    const bool isCol = lane < NW;
    const int  col   = lane & 31;
    float v_col   = isCol ? cmin : 0.0f;    // v = column min (feasible duals)
    float u_row   = 0.0f;
    int   win     = isCol ? rw[lane] : 64;
    int   col4row = (isCol && win < 64) ? win : -1;
    int   row4col = (isCol && rw[cargmin] == lane) ? cargmin : -1;
    __syncthreads();

    unsigned rem      = (unsigned)(__ballot(isCol && col4row < 0) & 0xffffffffull);
    unsigned freeCols = (unsigned)(__ballot(isCol && row4col < 0) & 0xffffffffull);

    // ------- Greedy free-row pass (ART-lite): u_i = min slack; assign if -------
    // the argmin column is free (edge tight, duals stay feasible).
    {
        unsigned g = rem;
        while (g != 0) {
            int i = __ffs(g) - 1;
            g &= (g - 1);
            float cij = cost[i][col];
            float slack = cij - v_col;                     // >= 0 (v = colmin)
            unsigned key = isCol
                ? ((__float_as_uint(slack) & 0xFFFFFFE0u) | (unsigned)col)
                : 0xFFFFFFFFu;
            unsigned kmin = wave_umin32_key(key);
            int   j1 = (int)(kmin & 31u);
            float m1 = __uint_as_float(kmin & 0xFFFFFFE0u);
            if (lane == i) u_row = m1;                     // tighten dual (feasible)
            if ((freeCols >> j1) & 1u) {                   // assign only if free
                if (lane == j1) row4col = i;
                if (lane == i)  col4row = j1;
                freeCols &= ~(1u << j1);
                rem      &= ~(1u << i);
            }
        }
    }

    // ------- Parallel JV reduction transfer (row-scan form) --------------------
    // For each assigned (i, j_i): delta_i = min_{j != j_i}(c_ij - v_j) - u_i;
    // u_i += delta_i; v_{j_i} -= delta_i. Tightens duals, keeps (i,j_i) tight
    // (up to float rounding; SAP's fmax clamp absorbs it). Effect: Dijkstra
    // distances to assigned columns only grow, free-column distances are
    // preserved (telescoping) => late SAP scans shrink. Unlike R4's serial
    // readlane loop this is straight-line per-lane work: lane i owns row i
    // (u_row layout), scans cost[i][*] from LDS (bank = (i+j)&31: conflict-
    // free), v mirrored via vsh. No loops, no steal, no cross-iteration dep.
    if (rem != 0) {
        if (isCol) vsh[col] = v_col;
        __syncthreads();
        const int irow = lane & 31;         // upper half duplicates; unused
        const int ji   = col4row;           // -1 for free rows / upper half
        float m0 = BIGF, m1 = BIGF, m2 = BIGF, m3 = BIGF;
        #pragma unroll
        for (int j = 0; j < NW; j += 4) {
            float s0 = cost[irow][j]     - vsh[j];
            float s1 = cost[irow][j + 1] - vsh[j + 1];
            float s2 = cost[irow][j + 2] - vsh[j + 2];
            float s3 = cost[irow][j + 3] - vsh[j + 3];
            m0 = fminf(m0, (ji == j)     ? BIGF : s0);
            m1 = fminf(m1, (ji == j + 1) ? BIGF : s1);
            m2 = fminf(m2, (ji == j + 2) ? BIGF : s2);
            m3 = fminf(m3, (ji == j + 3) ? BIGF : s3);
        }
        float delta = fmaxf(fminf(fminf(m0, m1), fminf(m2, m3)) - u_row, 0.0f);
        if (isCol && col4row >= 0) u_row += delta;
        float dsrc = __shfl(delta, (row4col >= 0) ? row4col : 0);
        if (isCol && row4col >= 0) v_col -= dsrc;
    }

    // ---------------- SAP: shortest augmenting path for leftover rows ----------
    {
        while (rem != 0) {
            int i0 = __ffs(rem) - 1;
            rem &= (rem - 1);

            bool     SCb     = !isCol;
            unsigned spcKey  = 0xFFFFFFFFu;    // (quantized slack | j), frozen at SC
            int      pathReg = 0;
            unsigned srMask  = 1u << i0;
            float    minValF = 0.0f;
            int      i = i0;
            int      sink;

            float cij = cost[i][col];          // prefetched cost row
            while (true) {
                float u_i = readlane_f(u_row, i);              // || with ds_read
                float t   = (minValF - v_col) - u_i;           // || with ds_read
                float slack = fmaxf(t + cij, 0.0f);            // >=0: bits monotone
                unsigned key = (__float_as_uint(slack) & 0xFFFFFFE0u) | (unsigned)col;
                unsigned old = spcKey;
                unsigned mn  = key < spcKey ? key : spcKey;
                spcKey = SCb ? spcKey : mn;                    // freeze when SC
                pathReg = (spcKey != old) ? i : pathReg;       // source row of best
                unsigned red = SCb ? 0xFFFFFFFFu : spcKey;

                unsigned kmin = wave_umin32_key(red);
                int j = (int)(kmin & 31u);                     // index in low bits
                minValF = __uint_as_float(kmin & 0xFFFFFFE0u); // value, quantized
                SCb = SCb || (lane == j);
                int r = __builtin_amdgcn_readlane(row4col, j); // || with bit test
                if ((freeCols >> j) & 1u) { sink = j; break; }
                i = r;
                srMask |= (1u << i);
                cij = cost[i][col];                            // prefetch next row
            }

            // dual updates (spc recovered from frozen keys, quantized)
            {
                float spcF = __uint_as_float(spcKey & 0xFFFFFFE0u);
                int gidx = (col4row < 0) ? 0 : col4row;
                float spc_at_c4r = __shfl(spcF, gidx);
                bool in_SR = isCol && ((srMask >> col) & 1u);
                if (lane == i0)              u_row += minValF;
                else if (in_SR)              u_row += minValF - spc_at_c4r;
                if (isCol && SCb)            v_col -= (minValF - spcF);
            }

            // augment along path
            {
                int j = sink;
                freeCols &= ~(1u << sink);
                while (true) {
                    int ii = __builtin_amdgcn_readlane(pathReg, j);
                    if (lane == j) row4col = ii;
                    int j_next = __builtin_amdgcn_readlane(col4row, ii);
                    if (lane == ii) col4row = j;
                    if (ii == i0) break;
                    j = j_next;
                }
            }
        }
    }

    // ---------------- Loss = sum of assigned edge costs ------------------------
    float myedge = (isCol && col4row >= 0) ? cost[lane][col4row] : 0.0f;
    #pragma unroll
    for (int off = 32; off >= 1; off >>= 1)
        myedge += __shfl_xor(myedge, off);
    if (lane == 0) out[b] = myedge;
}

extern "C" void kernel_launch(void* const* d_in, const int* in_sizes, int n_in,
                              void* d_out, int out_size, void* d_ws, size_t ws_size,
                              hipStream_t stream) {
    const float* params_true = (const float*)d_in[0];
    const float* params_pred = (const float*)d_in[1];
    float* out = (float*)d_out;
    floorplan_hungarian_kernel<<<BATCH, 64, 0, stream>>>(params_true, params_pred, out);
}